// Round 1
// baseline (487.215 us; speedup 1.0000x reference)
//
#include <hip/hip_runtime.h>
#include <stdint.h>

// SOM update: x (1024 f32), weights (65536x1024 f32), locations (65536 i32), it (1 i32)
// out: new_weights (65536x1024 f32)

#define N_ROWS 65536
#define DIM    1024
#define EPS    1e-6f
#define NITER  100.0f
#define ALPHA  0.3f
#define SIGMA  32768.0f

#define DIST_BLOCKS 2048   // 4 waves/block -> 8192 waves -> 8 rows/wave
#define ROWS_PER_WAVE (N_ROWS / (DIST_BLOCKS * 4))

// ---------------- Kernel 1: per-row distance + per-block argmin ----------------
__global__ __launch_bounds__(256) void som_dist(
    const float* __restrict__ x,
    const float* __restrict__ w,
    unsigned long long* __restrict__ part)
{
    const int lane = threadIdx.x & 63;
    const int wave = threadIdx.x >> 6;
    const int waveGlobal = blockIdx.x * 4 + wave;
    const int row0 = waveGlobal * ROWS_PER_WAVE;

    const float4* xv4 = (const float4*)x;   // 256 float4 per row

    unsigned long long best = ~0ull;

    for (int r = 0; r < ROWS_PER_WAVE; ++r) {
        const int row = row0 + r;
        const float4* wr = (const float4*)(w + (size_t)row * DIM);
        float s = 0.0f;
        #pragma unroll
        for (int p = 0; p < 4; ++p) {
            float4 wv = wr[p * 64 + lane];
            float4 xx = xv4[p * 64 + lane];
            float t;
            t = xx.x - wv.x + EPS; s = fmaf(t, t, s);
            t = xx.y - wv.y + EPS; s = fmaf(t, t, s);
            t = xx.z - wv.z + EPS; s = fmaf(t, t, s);
            t = xx.w - wv.w + EPS; s = fmaf(t, t, s);
        }
        // wave-wide sum (64 lanes)
        #pragma unroll
        for (int off = 32; off > 0; off >>= 1)
            s += __shfl_down(s, off, 64);
        if (lane == 0) {
            float d = sqrtf(s);  // d >= 0 so float bits are order-preserving
            unsigned long long enc =
                ((unsigned long long)__float_as_uint(d) << 32) | (unsigned)row;
            best = best < enc ? best : enc;
        }
    }

    __shared__ unsigned long long sm[4];
    if (lane == 0) sm[wave] = best;
    __syncthreads();
    if (threadIdx.x == 0) {
        unsigned long long b = sm[0];
        #pragma unroll
        for (int i = 1; i < 4; ++i) b = b < sm[i] ? b : sm[i];
        part[blockIdx.x] = b;
    }
}

// ---------------- Kernel 2: reduce 2048 partials -> winner at part[DIST_BLOCKS] ----------------
__global__ __launch_bounds__(256) void som_reduce(unsigned long long* __restrict__ part)
{
    __shared__ unsigned long long sm[256];
    unsigned long long b = ~0ull;
    for (int i = threadIdx.x; i < DIST_BLOCKS; i += 256) {
        unsigned long long v = part[i];
        b = b < v ? b : v;
    }
    sm[threadIdx.x] = b;
    __syncthreads();
    #pragma unroll
    for (int s = 128; s > 0; s >>= 1) {
        if (threadIdx.x < s) {
            unsigned long long v = sm[threadIdx.x + s];
            if (v < sm[threadIdx.x]) sm[threadIdx.x] = v;
        }
        __syncthreads();
    }
    if (threadIdx.x == 0) part[DIST_BLOCKS] = sm[0];
}

// ---------------- Kernel 3: update weights ----------------
__global__ __launch_bounds__(256) void som_update(
    const float* __restrict__ x,
    const float* __restrict__ w,
    const int* __restrict__ loc,
    const int* __restrict__ itp,
    const unsigned long long* __restrict__ winner,
    float* __restrict__ out)
{
    const int i = blockIdx.x * 256 + threadIdx.x;   // float4 index
    const int row  = i >> 8;                        // 256 float4 per row
    const int col4 = i & 255;

    const int bmu = (int)(unsigned)(winner[DIST_BLOCKS] & 0xffffffffull);

    const float lr       = 1.0f - (float)itp[0] / NITER;
    const float alpha_op = ALPHA * lr;
    const float sigma_op = SIGMA * lr;
    const float inv_s2   = 1.0f / (sigma_op * sigma_op);

    const float dloc  = (float)(loc[row] - bmu);
    const float neigh = expf(-(dloc * dloc) * inv_s2);
    const float lrm   = alpha_op * neigh;

    const float4 wv = ((const float4*)(w + (size_t)row * DIM))[col4];
    const float4 xx = ((const float4*)x)[col4];

    float4 o;
    o.x = fmaf(lrm, xx.x - wv.x, wv.x);
    o.y = fmaf(lrm, xx.y - wv.y, wv.y);
    o.z = fmaf(lrm, xx.z - wv.z, wv.z);
    o.w = fmaf(lrm, xx.w - wv.w, wv.w);

    ((float4*)(out + (size_t)row * DIM))[col4] = o;
}

extern "C" void kernel_launch(void* const* d_in, const int* in_sizes, int n_in,
                              void* d_out, int out_size, void* d_ws, size_t ws_size,
                              hipStream_t stream)
{
    const float* x  = (const float*)d_in[0];
    const float* w  = (const float*)d_in[1];
    const int* loc  = (const int*)d_in[2];
    const int* itp  = (const int*)d_in[3];
    float* out      = (float*)d_out;
    unsigned long long* part = (unsigned long long*)d_ws;  // [DIST_BLOCKS] partials + [1] winner

    som_dist<<<DIST_BLOCKS, 256, 0, stream>>>(x, w, part);
    som_reduce<<<1, 256, 0, stream>>>(part);

    const int total4 = N_ROWS * (DIM / 4);      // 16,777,216 float4
    som_update<<<total4 / 256, 256, 0, stream>>>(x, w, loc, itp, part, out);
}